// Round 10
// baseline (268.166 us; speedup 1.0000x reference)
//
#include <hip/hip_runtime.h>
#include <hip/hip_bf16.h>

#define NN 2560        // nodes
#define NE 163840      // edges
#define NH 4           // heads
#define NC 128         // channels per head
#define NF 512         // NH*NC
#define OUTE 40
#define CAPW 128       // per-wave register+LDS edge capacity (P[deg>128] ~ 0)

typedef short bf16x8 __attribute__((ext_vector_type(8)));
typedef float f32x4 __attribute__((ext_vector_type(4)));

__device__ inline ushort f2bf(float f) {
    uint u = __float_as_uint(f);
    uint r = u + 0x7FFF + ((u >> 16) & 1);   // round-to-nearest-even
    return (ushort)(r >> 16);
}
__device__ inline float bflo(uint v) { return __uint_as_float(v << 16); }
__device__ inline float bfhi(uint v) { return __uint_as_float(v & 0xFFFF0000u); }

// ---------------- kernel 1: fused prep (deg / dote / WfcT / W2T) ----------
// NOTE: grid.sync() cooperative variant measured at ~80us/sync on MI355X (R7)
// — separate small launches are strictly cheaper. Keep this non-cooperative.
__global__ void k_prep(const int* __restrict__ ei, int* __restrict__ deg,
                       const float* __restrict__ We1, const float* __restrict__ ae1,
                       const float* __restrict__ We2, const float* __restrict__ ae2,
                       float* __restrict__ dote,
                       const float* __restrict__ Wfc, ushort* __restrict__ WfcT,
                       const float* __restrict__ W2, ushort* __restrict__ W2T) {
    __shared__ ushort tile[64][72];
    int b = blockIdx.x;
    if (b < 640) {
        int e = b * 256 + threadIdx.x;
        atomicAdd(&deg[ei[NE + e]], 1);
    } else if (b < 642) {
        int t = threadIdx.x;
        const float* W = (b == 641) ? We2 : We1;
        const float* A = (b == 641) ? ae2 : ae1;
        int w = t >> 6, l = t & 63;
        float p = W[w * 128 + l] * A[w * 128 + l] + W[w * 128 + 64 + l] * A[w * 128 + 64 + l];
#pragma unroll
        for (int o = 32; o > 0; o >>= 1) p += __shfl_down(p, o);
        if (l == 0) dote[(b - 640) * 4 + w] = p;
    } else if (b < 738) {
        int idx = (b - 642) * 256 + threadIdx.x;    // j*512 + k
        int j = idx >> 9, k = idx & 511;
        WfcT[idx] = (j < OUTE) ? f2bf(Wfc[k * OUTE + j]) : (ushort)0;
    } else {
        int id = b - 738;
        int n0 = (id & 7) * 64, k0 = (id >> 3) * 64;
        int t = threadIdx.x;
        int r = t >> 2, cseg = (t & 3) * 16;
#pragma unroll
        for (int c = 0; c < 16; c += 4) {
            float4 v = *(const float4*)&W2[(k0 + r) * 512 + n0 + cseg + c];
            tile[cseg + c + 0][r] = f2bf(v.x);
            tile[cseg + c + 1][r] = f2bf(v.y);
            tile[cseg + c + 2][r] = f2bf(v.z);
            tile[cseg + c + 3][r] = f2bf(v.w);
        }
        __syncthreads();
        *(uint4*)&W2T[(n0 + r) * 512 + k0 + cseg]     = *(uint4*)&tile[r][cseg];
        *(uint4*)&W2T[(n0 + r) * 512 + k0 + cseg + 8] = *(uint4*)&tile[r][cseg + 8];
    }
}

// ---------------- kernel 2: exclusive scan of deg -> offs (single block) ---
__global__ void k_scan(const int* __restrict__ deg, int* __restrict__ offs) {
    __shared__ int cs[256];
    int t = threadIdx.x;
    int base = t * 10;
    int local[10];
    int s = 0;
#pragma unroll
    for (int i = 0; i < 10; i++) { local[i] = deg[base + i]; s += local[i]; }
    cs[t] = s;
    __syncthreads();
    for (int off = 1; off < 256; off <<= 1) {
        int v = (t >= off) ? cs[t - off] : 0;
        __syncthreads();
        cs[t] += v;
        __syncthreads();
    }
    int excl = (t == 0) ? 0 : cs[t - 1];
#pragma unroll
    for (int i = 0; i < 10; i++) { offs[base + i] = excl; excl += local[i]; }
    if (t == 255) offs[NN] = excl;
}

// ---------------- kernel 3: CSR fill, packed (src, ew) pairs --------------
__global__ void k_csr_fill(const int* __restrict__ ei, const float* __restrict__ pos,
                           const int* __restrict__ offs, int* __restrict__ cursor,
                           int2* __restrict__ csrp) {
    int e = blockIdx.x * 256 + threadIdx.x;
    if (e >= NE) return;
    int s = ei[e], d = ei[NE + e];
    float dx = pos[2 * s] - pos[2 * d];
    float dy = pos[2 * s + 1] - pos[2 * d + 1];
    float w = 1.0f / (sqrtf(dx * dx + dy * dy) + 1e-6f);
    int p = atomicAdd(&cursor[d], 1);
    csrp[offs[d] + p] = make_int2(s, __float_as_int(w));
}

// ---------------- kernel 4: fused GEMM1 + node-att (block per 4 nodes) ----
__global__ __launch_bounds__(256) void k_gemm1_att(const float* __restrict__ x,
        const float* __restrict__ W1, const float* __restrict__ atts,
        const float* __restrict__ attd, ushort* __restrict__ hb,
        float* __restrict__ as_, float* __restrict__ ad_) {
    __shared__ float s_x[4][32];
    __shared__ float4 s_red[4][4];     // [wave][node]
    int n0 = blockIdx.x * 4, t = threadIdx.x;
    if (t < 128) s_x[t >> 5][t & 31] = x[n0 * 32 + t];
    __syncthreads();
    float a0[4] = {0.f, 0.f, 0.f, 0.f}, a1[4] = {0.f, 0.f, 0.f, 0.f};
#pragma unroll
    for (int k = 0; k < 32; k++) {
        float w0 = W1[k * 512 + t];
        float w1 = W1[k * 512 + t + 256];
#pragma unroll
        for (int nn = 0; nn < 4; nn++) {
            a0[nn] += s_x[nn][k] * w0;
            a1[nn] += s_x[nn][k] * w1;
        }
    }
    float sa0 = atts[t], sa1 = atts[t + 256];
    float da0 = attd[t], da1 = attd[t + 256];
    int w = t >> 6, lane = t & 63;
#pragma unroll
    for (int nn = 0; nn < 4; nn++) {
        hb[(n0 + nn) * 512 + t] = f2bf(a0[nn]);
        hb[(n0 + nn) * 512 + t + 256] = f2bf(a1[nn]);
        float ps0 = a0[nn] * sa0, pd0 = a0[nn] * da0;
        float ps1 = a1[nn] * sa1, pd1 = a1[nn] * da1;
#pragma unroll
        for (int o = 32; o > 0; o >>= 1) {
            ps0 += __shfl_xor(ps0, o); pd0 += __shfl_xor(pd0, o);
            ps1 += __shfl_xor(ps1, o); pd1 += __shfl_xor(pd1, o);
        }
        if (lane == 0) s_red[w][nn] = make_float4(ps0, pd0, ps1, pd1);
    }
    __syncthreads();
    if (t < 4) {
        int nn = t, n = n0 + nn;
        float4 r0 = s_red[0][nn], r1 = s_red[1][nn], r2 = s_red[2][nn], r3 = s_red[3][nn];
        as_[n * 4 + 0] = r0.x + r1.x; as_[n * 4 + 1] = r2.x + r3.x;
        as_[n * 4 + 2] = r0.z + r1.z; as_[n * 4 + 3] = r2.z + r3.z;
        ad_[n * 4 + 0] = r0.y + r1.y; ad_[n * 4 + 1] = r2.y + r3.y;
        ad_[n * 4 + 2] = r0.w + r1.w; ad_[n * 4 + 3] = r2.w + r3.w;
    }
}

// ---------------- kernel 5: fused softmax+agg, ONE WAVE PER NODE ----------
// No __syncthreads anywhere: all reductions are 64-lane shuffles; the
// (off, alpha) edge table is wave-private LDS. 4 independent nodes/block.
__device__ inline float4 edge_logit(float4 a, float4 adv, float w,
                                    float d0, float d1, float d2, float d3) {
    float4 r; float v;
    v = a.x + adv.x + w * d0; r.x = v > 0.f ? v : 0.2f * v;
    v = a.y + adv.y + w * d1; r.y = v > 0.f ? v : 0.2f * v;
    v = a.z + adv.z + w * d2; r.z = v > 0.f ? v : 0.2f * v;
    v = a.w + adv.w + w * d3; r.w = v > 0.f ? v : 0.2f * v;
    return r;
}

__global__ __launch_bounds__(256, 4) void k_edge_agg(const int* __restrict__ offs,
        const int2* __restrict__ csrp, const float4* __restrict__ as4,
        const float4* __restrict__ ad4, const float* __restrict__ dote,
        const ushort* __restrict__ hb, const float* __restrict__ bias,
        float* __restrict__ out) {
    __shared__ float s_alh[4][4][CAPW];   // [wave][head][edge]
    __shared__ int s_off[4][CAPW];        // [wave][edge] src*NF element offsets
    int w = threadIdx.x >> 6, lane = threadIdx.x & 63;
    int n = blockIdx.x * 4 + w;
    int beg = offs[n], deg = offs[n + 1] - beg;
    float4 adv = ad4[n];
    float d0 = dote[0], d1 = dote[1], d2 = dote[2], d3 = dote[3];

    // ---- phase A: per-wave softmax entirely in registers ----
    float4 L0 = make_float4(-1e30f, -1e30f, -1e30f, -1e30f), L1 = L0;
    int off0 = 0, off1 = 0;
    if (lane < deg) {
        int2 p = csrp[beg + lane];
        off0 = p.x * NF;
        L0 = edge_logit(as4[p.x], adv, __int_as_float(p.y), d0, d1, d2, d3);
    }
    if (lane + 64 < deg) {
        int2 p = csrp[beg + lane + 64];
        off1 = p.x * NF;
        L1 = edge_logit(as4[p.x], adv, __int_as_float(p.y), d0, d1, d2, d3);
    }
    float4 m;
    m.x = fmaxf(L0.x, L1.x); m.y = fmaxf(L0.y, L1.y);
    m.z = fmaxf(L0.z, L1.z); m.w = fmaxf(L0.w, L1.w);
    for (int e = CAPW + lane; e < deg; e += 64) {     // cold: deg > 128
        int2 p = csrp[beg + e];
        float4 r = edge_logit(as4[p.x], adv, __int_as_float(p.y), d0, d1, d2, d3);
        m.x = fmaxf(m.x, r.x); m.y = fmaxf(m.y, r.y);
        m.z = fmaxf(m.z, r.z); m.w = fmaxf(m.w, r.w);
    }
#pragma unroll
    for (int o = 32; o > 0; o >>= 1) {
        m.x = fmaxf(m.x, __shfl_xor(m.x, o)); m.y = fmaxf(m.y, __shfl_xor(m.y, o));
        m.z = fmaxf(m.z, __shfl_xor(m.z, o)); m.w = fmaxf(m.w, __shfl_xor(m.w, o));
    }
    // exp: invalid lanes have L=-1e30 -> exp underflows to 0 (deg>0);
    // deg==0 gives acc=0 and out=bias regardless of denom. No masking needed.
    float4 A0, A1;
    A0.x = __expf(L0.x - m.x); A0.y = __expf(L0.y - m.y);
    A0.z = __expf(L0.z - m.z); A0.w = __expf(L0.w - m.w);
    A1.x = __expf(L1.x - m.x); A1.y = __expf(L1.y - m.y);
    A1.z = __expf(L1.z - m.z); A1.w = __expf(L1.w - m.w);
    float4 ss;
    ss.x = A0.x + A1.x; ss.y = A0.y + A1.y;
    ss.z = A0.z + A1.z; ss.w = A0.w + A1.w;
    for (int e = CAPW + lane; e < deg; e += 64) {     // cold recompute
        int2 p = csrp[beg + e];
        float4 r = edge_logit(as4[p.x], adv, __int_as_float(p.y), d0, d1, d2, d3);
        ss.x += __expf(r.x - m.x); ss.y += __expf(r.y - m.y);
        ss.z += __expf(r.z - m.z); ss.w += __expf(r.w - m.w);
    }
#pragma unroll
    for (int o = 32; o > 0; o >>= 1) {
        ss.x += __shfl_xor(ss.x, o); ss.y += __shfl_xor(ss.y, o);
        ss.z += __shfl_xor(ss.z, o); ss.w += __shfl_xor(ss.w, o);
    }
    // park (off, alpha) in wave-private LDS (no barrier needed: same wave)
    int mc = min(deg, CAPW);
    if (lane < mc) {
        s_off[w][lane] = off0;
        s_alh[w][0][lane] = A0.x; s_alh[w][1][lane] = A0.y;
        s_alh[w][2][lane] = A0.z; s_alh[w][3][lane] = A0.w;
    }
    if (lane + 64 < mc) {
        s_off[w][lane + 64] = off1;
        s_alh[w][0][lane + 64] = A1.x; s_alh[w][1][lane + 64] = A1.y;
        s_alh[w][2][lane + 64] = A1.z; s_alh[w][3][lane + 64] = A1.w;
    }

    // ---- phase B: stream rows; lane owns channels 8*lane..8*lane+7 ----
    int hd = lane >> 4;
    float inv = 1.f / (((const float*)&ss)[hd] + 1e-16f);
    float mxh = ((const float*)&m)[hd];
    const ushort* hbase = hb + 8 * lane;
    const float* alh = &s_alh[w][hd][0];
    float acc[8] = {0.f, 0.f, 0.f, 0.f, 0.f, 0.f, 0.f, 0.f};
    int e = 0;
    for (; e + 4 <= mc; e += 4) {
        float4 av = *(const float4*)&alh[e];          // 4-addr multicast LDS read
        int4 o4 = *(const int4*)&s_off[w][e];         // broadcast LDS read
        uint4 v0 = *(const uint4*)(hbase + o4.x);     // each: 1KB coalesced row
        uint4 v1 = *(const uint4*)(hbase + o4.y);
        uint4 v2 = *(const uint4*)(hbase + o4.z);
        uint4 v3 = *(const uint4*)(hbase + o4.w);
        acc[0] += av.x * bflo(v0.x) + av.y * bflo(v1.x) + av.z * bflo(v2.x) + av.w * bflo(v3.x);
        acc[1] += av.x * bfhi(v0.x) + av.y * bfhi(v1.x) + av.z * bfhi(v2.x) + av.w * bfhi(v3.x);
        acc[2] += av.x * bflo(v0.y) + av.y * bflo(v1.y) + av.z * bflo(v2.y) + av.w * bflo(v3.y);
        acc[3] += av.x * bfhi(v0.y) + av.y * bfhi(v1.y) + av.z * bfhi(v2.y) + av.w * bfhi(v3.y);
        acc[4] += av.x * bflo(v0.z) + av.y * bflo(v1.z) + av.z * bflo(v2.z) + av.w * bflo(v3.z);
        acc[5] += av.x * bfhi(v0.z) + av.y * bfhi(v1.z) + av.z * bfhi(v2.z) + av.w * bfhi(v3.z);
        acc[6] += av.x * bflo(v0.w) + av.y * bflo(v1.w) + av.z * bflo(v2.w) + av.w * bflo(v3.w);
        acc[7] += av.x * bfhi(v0.w) + av.y * bfhi(v1.w) + av.z * bfhi(v2.w) + av.w * bfhi(v3.w);
    }
    for (; e < mc; e++) {
        float a = alh[e];
        uint4 v = *(const uint4*)(hbase + s_off[w][e]);
        acc[0] += a * bflo(v.x); acc[1] += a * bfhi(v.x);
        acc[2] += a * bflo(v.y); acc[3] += a * bfhi(v.y);
        acc[4] += a * bflo(v.z); acc[5] += a * bfhi(v.z);
        acc[6] += a * bflo(v.w); acc[7] += a * bfhi(v.w);
    }
    for (int e2 = CAPW; e2 < deg; e2++) {             // cold: deg > 128
        int2 p = csrp[beg + e2];
        float4 r = edge_logit(as4[p.x], adv, __int_as_float(p.y), d0, d1, d2, d3);
        float c = hd == 0 ? r.x : hd == 1 ? r.y : hd == 2 ? r.z : r.w;
        float a = __expf(c - mxh);
        uint4 v = *(const uint4*)(hbase + p.x * NF);
        acc[0] += a * bflo(v.x); acc[1] += a * bfhi(v.x);
        acc[2] += a * bflo(v.y); acc[3] += a * bfhi(v.y);
        acc[4] += a * bflo(v.z); acc[5] += a * bfhi(v.z);
        acc[6] += a * bflo(v.w); acc[7] += a * bfhi(v.w);
    }
    // epilogue: normalize + bias, write 32B per lane
    float4 b0 = *(const float4*)&bias[8 * lane];
    float4 b1 = *(const float4*)&bias[8 * lane + 4];
    float4 o0 = make_float4(acc[0] * inv + b0.x, acc[1] * inv + b0.y,
                            acc[2] * inv + b0.z, acc[3] * inv + b0.w);
    float4 o1 = make_float4(acc[4] * inv + b1.x, acc[5] * inv + b1.y,
                            acc[6] * inv + b1.z, acc[7] * inv + b1.w);
    *(float4*)&out[n * NF + 8 * lane] = o0;
    *(float4*)&out[n * NF + 8 * lane + 4] = o1;
}

// ---------------- kernel 6: BN stats (block-local reduce, few atomics) ----
__global__ void k_bnstats(const float* __restrict__ x, float* __restrict__ stats) {
    int t = threadIdx.x;
    int r0 = blockIdx.x * 64;
    float s = 0.f, s2 = 0.f;
    for (int r = r0; r < r0 + 64; r++) {
        float v = x[r * NF + t];
        s += v; s2 += v * v;
    }
    atomicAdd(&stats[t], s);
    atomicAdd(&stats[NF + t], s2);
}

// ---------------- kernel 7: GEMM2 MFMA + inline BN1+relu + node-att -------
__global__ __launch_bounds__(256) void k_gemm2_bn_att(const float* __restrict__ A,
        const float* __restrict__ stats, const float* __restrict__ g,
        const float* __restrict__ bb, const ushort* __restrict__ BT,
        const float* __restrict__ atts, const float* __restrict__ attd,
        ushort* __restrict__ Cb, float* __restrict__ as_, float* __restrict__ ad_) {
    __shared__ ushort As[128][40];   // [m][k], +8 pad
    __shared__ ushort Bs[128][40];   // [n][k], +8 pad
    __shared__ float s_scale[512], s_shift[512];
    __shared__ float s_ps[2][128], s_pd[2][128];
    int t = threadIdx.x;
    const float invn = 1.0f / (float)NN;
    {
        int j = t;
#pragma unroll
        for (int rep = 0; rep < 2; rep++, j += 256) {
            float mu = stats[j] * invn;
            float var = stats[NF + j] * invn - mu * mu;
            float sc = rsqrtf(var + 1e-5f) * g[j];
            s_scale[j] = sc;
            s_shift[j] = bb[j] - mu * sc;
        }
    }
    int head = blockIdx.x;
    int rowBase = blockIdx.y * 128, colBase = head * 128;
    int w = t >> 6, lane = t & 63;
    int wm = (w >> 1) * 64, wn = (w & 1) * 64;
    int lm = lane & 15, q = lane >> 4;
    f32x4 acc[4][4] = {};
    int sr = t >> 2, sk = (t & 3) * 8;
    for (int k0 = 0; k0 < 512; k0 += 32) {
        __syncthreads();
        int jb = k0 + sk;
        float sc[8], sh[8];
#pragma unroll
        for (int c = 0; c < 8; c++) { sc[c] = s_scale[jb + c]; sh[c] = s_shift[jb + c]; }
        const float* Ap0 = &A[(rowBase + sr) * 512 + jb];
        const float* Ap1 = Ap0 + 64 * 512;
        float4 a00 = *(const float4*)Ap0, a01 = *(const float4*)(Ap0 + 4);
        float4 a10 = *(const float4*)Ap1, a11 = *(const float4*)(Ap1 + 4);
        uint4 b0 = *(const uint4*)&BT[(colBase + sr) * 512 + jb];
        uint4 b1 = *(const uint4*)&BT[(colBase + 64 + sr) * 512 + jb];
        ushort pa0[8], pa1[8];
        const float* f0 = &a00.x; const float* f1 = &a10.x;
#pragma unroll
        for (int c = 0; c < 4; c++) {
            pa0[c] = f2bf(fmaxf(f0[c] * sc[c] + sh[c], 0.f));
            pa1[c] = f2bf(fmaxf(f1[c] * sc[c] + sh[c], 0.f));
        }
        const float* f2 = &a01.x; const float* f3 = &a11.x;
#pragma unroll
        for (int c = 0; c < 4; c++) {
            pa0[4 + c] = f2bf(fmaxf(f2[c] * sc[4 + c] + sh[4 + c], 0.f));
            pa1[4 + c] = f2bf(fmaxf(f3[c] * sc[4 + c] + sh[4 + c], 0.f));
        }
        *(uint4*)&As[sr][sk]      = *(uint4*)pa0;
        *(uint4*)&As[64 + sr][sk] = *(uint4*)pa1;
        *(uint4*)&Bs[sr][sk]      = b0;
        *(uint4*)&Bs[64 + sr][sk] = b1;
        __syncthreads();
        bf16x8 af[4], bf[4];
#pragma unroll
        for (int i = 0; i < 4; i++) af[i] = *(const bf16x8*)&As[wm + i * 16 + lm][q * 8];
#pragma unroll
        for (int j = 0; j < 4; j++) bf[j] = *(const bf16x8*)&Bs[wn + j * 16 + lm][q * 8];
#pragma unroll
        for (int i = 0; i < 4; i++)
#pragma unroll
            for (int j = 0; j < 4; j++)
                acc[i][j] = __builtin_amdgcn_mfma_f32_16x16x32_bf16(af[i], bf[j], acc[i][j], 0, 0, 0);
    }
    // C store (bf16)
#pragma unroll
    for (int i = 0; i < 4; i++) {
        int row = rowBase + wm + i * 16 + q * 4;
#pragma unroll
        for (int j = 0; j < 4; j++) {
            int col = colBase + wn + j * 16 + lm;
#pragma unroll
            for (int r = 0; r < 4; r++)
                Cb[(row + r) * 512 + col] = f2bf(acc[i][j][r]);
        }
    }
    // node-att epilogue: complete head dot for this block's 128 rows
    float sa[4], da[4];
#pragma unroll
    for (int j = 0; j < 4; j++) {
        int col = colBase + wn + j * 16 + lm;
        sa[j] = atts[col]; da[j] = attd[col];
    }
#pragma unroll
    for (int i = 0; i < 4; i++) {
#pragma unroll
        for (int r = 0; r < 4; r++) {
            float ps = 0.f, pd = 0.f;
#pragma unroll
            for (int j = 0; j < 4; j++) {
                float c = acc[i][j][r];
                ps += c * sa[j]; pd += c * da[j];
            }
#pragma unroll
            for (int o = 1; o < 16; o <<= 1) { ps += __shfl_xor(ps, o); pd += __shfl_xor(pd, o); }
            if (lm == 0) {
                int row = wm + i * 16 + q * 4 + r;
                s_ps[w & 1][row] = ps; s_pd[w & 1][row] = pd;
            }
        }
    }
    __syncthreads();
    if (t < 128) {
        as_[(rowBase + t) * 4 + head] = s_ps[0][t] + s_ps[1][t];
    } else {
        int row = t - 128;
        ad_[(rowBase + row) * 4 + head] = s_pd[0][row] + s_pd[1][row];
    }
}

// ---------------- kernel 8: FC MFMA with inline BN2+relu + mask + adj -----
__global__ __launch_bounds__(64) void k_fc_bn(const float* __restrict__ e2,
        const float* __restrict__ stats, const float* __restrict__ g,
        const float* __restrict__ bb, const ushort* __restrict__ WfcT,
        const float* __restrict__ bfc, const int* __restrict__ mask,
        const float* __restrict__ adj, float* __restrict__ out) {
    __shared__ float s_scale[512], s_shift[512];
    int lane = threadIdx.x;
    const float invn = 1.0f / (float)NN;
    for (int j = lane; j < 512; j += 64) {
        float mu = stats[j] * invn;
        float var = stats[NF + j] * invn - mu * mu;
        float sc = rsqrtf(var + 1e-5f) * g[j];
        s_scale[j] = sc;
        s_shift[j] = bb[j] - mu * sc;
    }
    __syncthreads();
    int r0 = blockIdx.x * 16;
    int lm = lane & 15, q = lane >> 4;
    f32x4 acc[3] = {};
#pragma unroll
    for (int k0 = 0; k0 < 512; k0 += 32) {
        int jb = k0 + q * 8;
        const float* p = &e2[(r0 + lm) * 512 + jb];
        float4 v0 = *(const float4*)p, v1 = *(const float4*)(p + 4);
        ushort pa[8];
        const float* f0 = &v0.x; const float* f1 = &v1.x;
#pragma unroll
        for (int c = 0; c < 4; c++) {
            pa[c]     = f2bf(fmaxf(f0[c] * s_scale[jb + c] + s_shift[jb + c], 0.f));
            pa[4 + c] = f2bf(fmaxf(f1[c] * s_scale[jb + 4 + c] + s_shift[jb + 4 + c], 0.f));
        }
        bf16x8 af = *(const bf16x8*)pa;
#pragma unroll
        for (int jt = 0; jt < 3; jt++) {
            bf16x8 bf = *(const bf16x8*)&WfcT[(jt * 16 + lm) * 512 + k0 + q * 8];
            acc[jt] = __builtin_amdgcn_mfma_f32_16x16x32_bf16(af, bf, acc[jt], 0, 0, 0);
        }
    }
#pragma unroll
    for (int jt = 0; jt < 3; jt++) {
        int col = jt * 16 + lm;
        if (col < OUTE) {
#pragma unroll
            for (int r = 0; r < 4; r++) {
                int n = r0 + q * 4 + r;
                float v = acc[jt][r] + bfc[col];
                v = mask[n] ? v : 0.f;
                out[n * OUTE + col] = v + adj[n * OUTE + col];
            }
        }
    }
}

// ---------------- host side ----------------------------------------------
extern "C" void kernel_launch(void* const* d_in, const int* in_sizes, int n_in,
                              void* d_out, int out_size, void* d_ws, size_t ws_size,
                              hipStream_t stream) {
    const float* x       = (const float*)d_in[0];
    const int*   ei      = (const int*)d_in[1];
    const float* pos     = (const float*)d_in[2];
    const int*   mask    = (const int*)d_in[3];
    const float* adj     = (const float*)d_in[4];
    const float* W1      = (const float*)d_in[5];
    const float* atts1   = (const float*)d_in[6];
    const float* attd1   = (const float*)d_in[7];
    const float* We1     = (const float*)d_in[8];
    const float* atte1   = (const float*)d_in[9];
    const float* bias1   = (const float*)d_in[10];
    const float* g1      = (const float*)d_in[11];
    const float* be1     = (const float*)d_in[12];
    const float* W2      = (const float*)d_in[13];
    const float* atts2   = (const float*)d_in[14];
    const float* attd2   = (const float*)d_in[15];
    const float* We2     = (const float*)d_in[16];
    const float* atte2   = (const float*)d_in[17];
    const float* bias2   = (const float*)d_in[18];
    const float* g2      = (const float*)d_in[19];
    const float* be2     = (const float*)d_in[20];
    const float* Wfc     = (const float*)d_in[21];
    const float* bfc     = (const float*)d_in[22];
    float* out = (float*)d_out;

    // workspace layout (float-element offsets; 16B-aligned blocks)
    char* ws = (char*)d_ws;
    int*    deg     = (int*)(ws);                       // 2560
    int*    cursor  = (int*)(ws + 2560 * 4);            // 2560
    float*  stats   = (float*)(ws + 5120 * 4);          // 2048 (L1:1024, L2:1024)
    // ---- zero region = first 7168 elements ----
    int*    offs    = (int*)(ws + 7168 * 4);            // 2561 (pad to 2576)
    float*  dote    = (float*)(ws + 9744 * 4);          // 8 (pad 16)
    int2*   csrp    = (int2*)(ws + 9760 * 4);           // 163840 int2 = 327680 ints
    float*  as_     = (float*)(ws + 337440 * 4);        // 10240
    float*  ad_     = (float*)(ws + 347680 * 4);        // 10240
    float*  t1      = (float*)(ws + 357920 * 4);        // 1310720 (agg out, BN input)
    ushort* hb      = (ushort*)(ws + 1668640 * 4);      // 1310720 bf16 (h for agg/att)
    ushort* W2T     = (ushort*)(ws + 2324000 * 4);      // 262144 bf16
    ushort* WfcT    = (ushort*)(ws + 2455072 * 4);      // 24576 bf16 [48][512]
    // total ~2.47M floats = ~9.9 MB

    hipMemsetAsync(d_ws, 0, 7168 * 4, stream);

    // graph structure + weight prep (separate launches — see R7 note)
    k_prep<<<802, 256, 0, stream>>>(ei, deg, We1, atte1, We2, atte2, dote, Wfc, WfcT, W2, W2T);
    k_scan<<<1, 256, 0, stream>>>(deg, offs);
    k_csr_fill<<<NE / 256, 256, 0, stream>>>(ei, pos, offs, cursor, csrp);

    // ---- layer 1 ----
    k_gemm1_att<<<NN / 4, 256, 0, stream>>>(x, W1, atts1, attd1, hb, as_, ad_);
    k_edge_agg<<<NN / 4, 256, 0, stream>>>(offs, csrp, (const float4*)as_,
                                           (const float4*)ad_, dote, hb, bias1, t1);
    k_bnstats<<<NN / 64, 512, 0, stream>>>(t1, stats);

    // ---- layer 2 (BN1 inline in GEMM2 A-staging; node-att in epilogue) ----
    k_gemm2_bn_att<<<dim3(4, NN / 128), 256, 0, stream>>>(t1, stats, g1, be1, W2T,
                                                          atts2, attd2, hb, as_, ad_);
    k_edge_agg<<<NN / 4, 256, 0, stream>>>(offs, csrp, (const float4*)as_,
                                           (const float4*)ad_, dote + 4, hb, bias2, t1);
    k_bnstats<<<NN / 64, 512, 0, stream>>>(t1, stats + 1024);

    // ---- head (BN2 inline in FC A-fragment load) ----
    k_fc_bn<<<NN / 16, 64, 0, stream>>>(t1, stats + 1024, g2, be2, WfcT, bfc, mask, adj, out);
}

// Round 11
// 247.925 us; speedup vs baseline: 1.0816x; 1.0816x over previous
//
#include <hip/hip_runtime.h>
#include <hip/hip_bf16.h>

#define NN 2560        // nodes
#define NE 163840      // edges
#define NH 4           // heads
#define NC 128         // channels per head
#define NF 512         // NH*NC
#define OUTE 40
#define CAP 320        // LDS edge capacity per node in fused edge kernel

typedef short bf16x8 __attribute__((ext_vector_type(8)));
typedef float f32x4 __attribute__((ext_vector_type(4)));

__device__ inline ushort f2bf(float f) {
    uint u = __float_as_uint(f);
    uint r = u + 0x7FFF + ((u >> 16) & 1);   // round-to-nearest-even
    return (ushort)(r >> 16);
}
__device__ inline float bflo(uint v) { return __uint_as_float(v << 16); }
__device__ inline float bfhi(uint v) { return __uint_as_float(v & 0xFFFF0000u); }

// ---------------- kernel 1: fused prep (deg / dote / WfcT / W2T) ----------
// NOTE: grid.sync() cooperative variant measured at ~80us/sync on MI355X (R7)
// — separate small launches are strictly cheaper. Keep this non-cooperative.
__global__ void k_prep(const int* __restrict__ ei, int* __restrict__ deg,
                       const float* __restrict__ We1, const float* __restrict__ ae1,
                       const float* __restrict__ We2, const float* __restrict__ ae2,
                       float* __restrict__ dote,
                       const float* __restrict__ Wfc, ushort* __restrict__ WfcT,
                       const float* __restrict__ W2, ushort* __restrict__ W2T) {
    __shared__ ushort tile[64][72];
    int b = blockIdx.x;
    if (b < 640) {
        int e = b * 256 + threadIdx.x;
        atomicAdd(&deg[ei[NE + e]], 1);
    } else if (b < 642) {
        int t = threadIdx.x;
        const float* W = (b == 641) ? We2 : We1;
        const float* A = (b == 641) ? ae2 : ae1;
        int w = t >> 6, l = t & 63;
        float p = W[w * 128 + l] * A[w * 128 + l] + W[w * 128 + 64 + l] * A[w * 128 + 64 + l];
#pragma unroll
        for (int o = 32; o > 0; o >>= 1) p += __shfl_down(p, o);
        if (l == 0) dote[(b - 640) * 4 + w] = p;
    } else if (b < 738) {
        int idx = (b - 642) * 256 + threadIdx.x;    // j*512 + k
        int j = idx >> 9, k = idx & 511;
        WfcT[idx] = (j < OUTE) ? f2bf(Wfc[k * OUTE + j]) : (ushort)0;
    } else {
        int id = b - 738;
        int n0 = (id & 7) * 64, k0 = (id >> 3) * 64;
        int t = threadIdx.x;
        int r = t >> 2, cseg = (t & 3) * 16;
#pragma unroll
        for (int c = 0; c < 16; c += 4) {
            float4 v = *(const float4*)&W2[(k0 + r) * 512 + n0 + cseg + c];
            tile[cseg + c + 0][r] = f2bf(v.x);
            tile[cseg + c + 1][r] = f2bf(v.y);
            tile[cseg + c + 2][r] = f2bf(v.z);
            tile[cseg + c + 3][r] = f2bf(v.w);
        }
        __syncthreads();
        *(uint4*)&W2T[(n0 + r) * 512 + k0 + cseg]     = *(uint4*)&tile[r][cseg];
        *(uint4*)&W2T[(n0 + r) * 512 + k0 + cseg + 8] = *(uint4*)&tile[r][cseg + 8];
    }
}

// ---------------- kernel 2: exclusive scan of deg -> offs (single block) ---
__global__ void k_scan(const int* __restrict__ deg, int* __restrict__ offs) {
    __shared__ int cs[256];
    int t = threadIdx.x;
    int base = t * 10;
    int local[10];
    int s = 0;
#pragma unroll
    for (int i = 0; i < 10; i++) { local[i] = deg[base + i]; s += local[i]; }
    cs[t] = s;
    __syncthreads();
    for (int off = 1; off < 256; off <<= 1) {
        int v = (t >= off) ? cs[t - off] : 0;
        __syncthreads();
        cs[t] += v;
        __syncthreads();
    }
    int excl = (t == 0) ? 0 : cs[t - 1];
#pragma unroll
    for (int i = 0; i < 10; i++) { offs[base + i] = excl; excl += local[i]; }
    if (t == 255) offs[NN] = excl;
}

// ---------------- kernel 3: CSR fill, packed (src, ew) pairs --------------
__global__ void k_csr_fill(const int* __restrict__ ei, const float* __restrict__ pos,
                           const int* __restrict__ offs, int* __restrict__ cursor,
                           int2* __restrict__ csrp) {
    int e = blockIdx.x * 256 + threadIdx.x;
    if (e >= NE) return;
    int s = ei[e], d = ei[NE + e];
    float dx = pos[2 * s] - pos[2 * d];
    float dy = pos[2 * s + 1] - pos[2 * d + 1];
    float w = 1.0f / (sqrtf(dx * dx + dy * dy) + 1e-6f);
    int p = atomicAdd(&cursor[d], 1);
    csrp[offs[d] + p] = make_int2(s, __float_as_int(w));
}

// ---------------- kernel 4: fused GEMM1 + node-att (block per 4 nodes) ----
__global__ __launch_bounds__(256) void k_gemm1_att(const float* __restrict__ x,
        const float* __restrict__ W1, const float* __restrict__ atts,
        const float* __restrict__ attd, ushort* __restrict__ hb,
        float* __restrict__ as_, float* __restrict__ ad_) {
    __shared__ float s_x[4][32];
    __shared__ float4 s_red[4][4];     // [wave][node]
    int n0 = blockIdx.x * 4, t = threadIdx.x;
    if (t < 128) s_x[t >> 5][t & 31] = x[n0 * 32 + t];
    __syncthreads();
    float a0[4] = {0.f, 0.f, 0.f, 0.f}, a1[4] = {0.f, 0.f, 0.f, 0.f};
#pragma unroll
    for (int k = 0; k < 32; k++) {
        float w0 = W1[k * 512 + t];
        float w1 = W1[k * 512 + t + 256];
#pragma unroll
        for (int nn = 0; nn < 4; nn++) {
            a0[nn] += s_x[nn][k] * w0;
            a1[nn] += s_x[nn][k] * w1;
        }
    }
    float sa0 = atts[t], sa1 = atts[t + 256];
    float da0 = attd[t], da1 = attd[t + 256];
    int w = t >> 6, lane = t & 63;
#pragma unroll
    for (int nn = 0; nn < 4; nn++) {
        hb[(n0 + nn) * 512 + t] = f2bf(a0[nn]);
        hb[(n0 + nn) * 512 + t + 256] = f2bf(a1[nn]);
        float ps0 = a0[nn] * sa0, pd0 = a0[nn] * da0;
        float ps1 = a1[nn] * sa1, pd1 = a1[nn] * da1;
#pragma unroll
        for (int o = 32; o > 0; o >>= 1) {
            ps0 += __shfl_xor(ps0, o); pd0 += __shfl_xor(pd0, o);
            ps1 += __shfl_xor(ps1, o); pd1 += __shfl_xor(pd1, o);
        }
        if (lane == 0) s_red[w][nn] = make_float4(ps0, pd0, ps1, pd1);
    }
    __syncthreads();
    if (t < 4) {
        int nn = t, n = n0 + nn;
        float4 r0 = s_red[0][nn], r1 = s_red[1][nn], r2 = s_red[2][nn], r3 = s_red[3][nn];
        as_[n * 4 + 0] = r0.x + r1.x; as_[n * 4 + 1] = r2.x + r3.x;
        as_[n * 4 + 2] = r0.z + r1.z; as_[n * 4 + 3] = r2.z + r3.z;
        ad_[n * 4 + 0] = r0.y + r1.y; ad_[n * 4 + 1] = r2.y + r3.y;
        ad_[n * 4 + 2] = r0.w + r1.w; ad_[n * 4 + 3] = r2.w + r3.w;
    }
}

// ---------------- kernel 5: fused logits+softmax+aggregation --------------
__device__ inline float4 edge_logit(float4 a, float4 adv, float w,
                                    float d0, float d1, float d2, float d3) {
    float4 r; float v;
    v = a.x + adv.x + w * d0; r.x = v > 0.f ? v : 0.2f * v;
    v = a.y + adv.y + w * d1; r.y = v > 0.f ? v : 0.2f * v;
    v = a.z + adv.z + w * d2; r.z = v > 0.f ? v : 0.2f * v;
    v = a.w + adv.w + w * d3; r.w = v > 0.f ? v : 0.2f * v;
    return r;
}

#define CONSUME(av, v0, v1, v2, v3)                                                              \
    acc[0] += av.x * bflo(v0.x) + av.y * bflo(v1.x) + av.z * bflo(v2.x) + av.w * bflo(v3.x);     \
    acc[1] += av.x * bfhi(v0.x) + av.y * bfhi(v1.x) + av.z * bfhi(v2.x) + av.w * bfhi(v3.x);     \
    acc[2] += av.x * bflo(v0.y) + av.y * bflo(v1.y) + av.z * bflo(v2.y) + av.w * bflo(v3.y);     \
    acc[3] += av.x * bfhi(v0.y) + av.y * bfhi(v1.y) + av.z * bfhi(v2.y) + av.w * bfhi(v3.y);     \
    acc[4] += av.x * bflo(v0.z) + av.y * bflo(v1.z) + av.z * bflo(v2.z) + av.w * bflo(v3.z);     \
    acc[5] += av.x * bfhi(v0.z) + av.y * bfhi(v1.z) + av.z * bfhi(v2.z) + av.w * bfhi(v3.z);     \
    acc[6] += av.x * bflo(v0.w) + av.y * bflo(v1.w) + av.z * bflo(v2.w) + av.w * bflo(v3.w);     \
    acc[7] += av.x * bfhi(v0.w) + av.y * bfhi(v1.w) + av.z * bfhi(v2.w) + av.w * bfhi(v3.w)

// phase 3: partition = wave; lane owns channels 8*lane..8*lane+7 (uint4 = 16B)
// -> one wave load insn covers a full 1KB hb row. Double-buffered prefetch:
// batch i+1's LDS reads + 4 row loads are issued BEFORE consuming batch i,
// keeping 8 row-loads in flight per wave (breaks the per-batch vmcnt(0) chain).
__global__ __launch_bounds__(256, 4) void k_edge_agg(const int* __restrict__ offs,
        const int2* __restrict__ csrp, const float4* __restrict__ as4,
        const float4* __restrict__ ad4, const float* __restrict__ dote,
        const ushort* __restrict__ hb, const float* __restrict__ bias,
        float* __restrict__ out) {
    __shared__ int s_off[CAP];         // precomputed src*NF element offsets
    __shared__ float s_al[4][CAP];     // head-major alpha
    __shared__ float s_part[4][512];   // per-partition channel partials
    __shared__ float4 s_red4[4];
    __shared__ float4 s_mx, s_dn;
    int n = blockIdx.x, t = threadIdx.x;
    int w = t >> 6, lane = t & 63;
    int beg = offs[n], deg = offs[n + 1] - beg;
    float4 adv = ad4[n];
    float d0 = dote[0], d1 = dote[1], d2 = dote[2], d3 = dote[3];
    // phase 1: logits -> LDS, track max
    float4 m = make_float4(-1e30f, -1e30f, -1e30f, -1e30f);
    for (int e = t; e < deg; e += 256) {
        int2 p = csrp[beg + e];
        float4 r = edge_logit(as4[p.x], adv, __int_as_float(p.y), d0, d1, d2, d3);
        if (e < CAP) {
            s_off[e] = p.x * NF;
            s_al[0][e] = r.x; s_al[1][e] = r.y; s_al[2][e] = r.z; s_al[3][e] = r.w;
        }
        m.x = fmaxf(m.x, r.x); m.y = fmaxf(m.y, r.y);
        m.z = fmaxf(m.z, r.z); m.w = fmaxf(m.w, r.w);
    }
#pragma unroll
    for (int o = 32; o > 0; o >>= 1) {
        m.x = fmaxf(m.x, __shfl_xor(m.x, o)); m.y = fmaxf(m.y, __shfl_xor(m.y, o));
        m.z = fmaxf(m.z, __shfl_xor(m.z, o)); m.w = fmaxf(m.w, __shfl_xor(m.w, o));
    }
    if (lane == 0) s_red4[w] = m;
    __syncthreads();
    if (t == 0) {
        float4 a = s_red4[0], b = s_red4[1], c = s_red4[2], d = s_red4[3];
        s_mx = make_float4(fmaxf(fmaxf(a.x, b.x), fmaxf(c.x, d.x)),
                           fmaxf(fmaxf(a.y, b.y), fmaxf(c.y, d.y)),
                           fmaxf(fmaxf(a.z, b.z), fmaxf(c.z, d.z)),
                           fmaxf(fmaxf(a.w, b.w), fmaxf(c.w, d.w)));
    }
    __syncthreads();
    float4 mx = s_mx;
    // phase 2: exp + denominator (deg<=CAP always in practice -> LDS-only)
    float4 ss = make_float4(0.f, 0.f, 0.f, 0.f);
    for (int e = t; e < deg; e += 256) {
        float4 r;
        if (e < CAP) { r.x = s_al[0][e]; r.y = s_al[1][e]; r.z = s_al[2][e]; r.w = s_al[3][e]; }
        else {
            int2 p = csrp[beg + e];
            r = edge_logit(as4[p.x], adv, __int_as_float(p.y), d0, d1, d2, d3);
        }
        r.x = __expf(r.x - mx.x); r.y = __expf(r.y - mx.y);
        r.z = __expf(r.z - mx.z); r.w = __expf(r.w - mx.w);
        if (e < CAP) { s_al[0][e] = r.x; s_al[1][e] = r.y; s_al[2][e] = r.z; s_al[3][e] = r.w; }
        ss.x += r.x; ss.y += r.y; ss.z += r.z; ss.w += r.w;
    }
#pragma unroll
    for (int o = 32; o > 0; o >>= 1) {
        ss.x += __shfl_xor(ss.x, o); ss.y += __shfl_xor(ss.y, o);
        ss.z += __shfl_xor(ss.z, o); ss.w += __shfl_xor(ss.w, o);
    }
    if (lane == 0) s_red4[w] = ss;
    __syncthreads();
    if (t == 0) {
        float4 a = s_red4[0], b = s_red4[1], c = s_red4[2], d = s_red4[3];
        s_dn = make_float4(a.x + b.x + c.x + d.x, a.y + b.y + c.y + d.y,
                           a.z + b.z + c.z + d.z, a.w + b.w + c.w + d.w);
    }
    __syncthreads();
    // phase 3: partition = wave w; lane tc owns 8 channels (uint4 gathers)
    int part = w;
    int tc = lane;               // 0..63
    int hd = tc >> 4;            // head of channels 8tc..8tc+7
    float mxh = ((const float*)&mx)[hd];
    const float* al = &s_al[hd][0];
    const ushort* hbase = hb + 8 * tc;
    float acc[8] = {0.f, 0.f, 0.f, 0.f, 0.f, 0.f, 0.f, 0.f};
    int mcap = min(deg, CAP);
    int q4 = (mcap / 4) & ~3;
    int eb = part * q4;
    int ee = (part == 3) ? mcap : eb + q4;
    int e = eb;
    int nfull = (ee - eb) >> 2;
    if (nfull > 0) {
        // prologue: batch 0 in flight
        float4 av = *(const float4*)&al[e];
        int4 o4 = *(const int4*)&s_off[e];
        uint4 v0 = *(const uint4*)(hbase + o4.x);
        uint4 v1 = *(const uint4*)(hbase + o4.y);
        uint4 v2 = *(const uint4*)(hbase + o4.z);
        uint4 v3 = *(const uint4*)(hbase + o4.w);
        for (int b = 1; b < nfull; b++) {
            // issue batch b's loads before consuming batch b-1
            float4 avn = *(const float4*)&al[e + 4];
            int4 o4n = *(const int4*)&s_off[e + 4];
            uint4 n0 = *(const uint4*)(hbase + o4n.x);
            uint4 n1 = *(const uint4*)(hbase + o4n.y);
            uint4 n2 = *(const uint4*)(hbase + o4n.z);
            uint4 n3 = *(const uint4*)(hbase + o4n.w);
            CONSUME(av, v0, v1, v2, v3);
            av = avn; v0 = n0; v1 = n1; v2 = n2; v3 = n3;
            e += 4;
        }
        CONSUME(av, v0, v1, v2, v3);
        e += 4;
    }
    for (; e < ee; e++) {
        float a = al[e];
        uint4 v = *(const uint4*)(hbase + s_off[e]);
        acc[0] += a * bflo(v.x); acc[1] += a * bfhi(v.x);
        acc[2] += a * bflo(v.y); acc[3] += a * bfhi(v.y);
        acc[4] += a * bflo(v.z); acc[5] += a * bfhi(v.z);
        acc[6] += a * bflo(v.w); acc[7] += a * bfhi(v.w);
    }
    // cold overflow path (deg > CAP): recompute logits, parts interleave
    for (int e2 = CAP + part; e2 < deg; e2 += 4) {
        int2 p = csrp[beg + e2];
        float4 r = edge_logit(as4[p.x], adv, __int_as_float(p.y), d0, d1, d2, d3);
        float c = hd == 0 ? r.x : hd == 1 ? r.y : hd == 2 ? r.z : r.w;
        float a = __expf(c - mxh);
        uint4 v = *(const uint4*)(hbase + p.x * NF);
        acc[0] += a * bflo(v.x); acc[1] += a * bfhi(v.x);
        acc[2] += a * bflo(v.y); acc[3] += a * bfhi(v.y);
        acc[4] += a * bflo(v.z); acc[5] += a * bfhi(v.z);
        acc[6] += a * bflo(v.w); acc[7] += a * bfhi(v.w);
    }
    *(float4*)&s_part[part][8 * tc]     = make_float4(acc[0], acc[1], acc[2], acc[3]);
    *(float4*)&s_part[part][8 * tc + 4] = make_float4(acc[4], acc[5], acc[6], acc[7]);
    __syncthreads();
    // final: 2 channels per thread, sum 4 partitions, normalize + bias
    {
        int ch = 2 * t;
        int hd2 = ch >> 7;
        float inv = 1.f / (((const float*)&s_dn)[hd2] + 1e-16f);
        float2 p0 = *(const float2*)&s_part[0][ch];
        float2 p1 = *(const float2*)&s_part[1][ch];
        float2 p2 = *(const float2*)&s_part[2][ch];
        float2 p3 = *(const float2*)&s_part[3][ch];
        float v0 = (p0.x + p1.x + p2.x + p3.x) * inv + bias[ch];
        float v1 = (p0.y + p1.y + p2.y + p3.y) * inv + bias[ch + 1];
        *(float2*)&out[n * NF + ch] = make_float2(v0, v1);
    }
}

// ---------------- kernel 6: BN stats (block-local reduce, few atomics) ----
__global__ void k_bnstats(const float* __restrict__ x, float* __restrict__ stats) {
    int t = threadIdx.x;
    int r0 = blockIdx.x * 64;
    float s = 0.f, s2 = 0.f;
    for (int r = r0; r < r0 + 64; r++) {
        float v = x[r * NF + t];
        s += v; s2 += v * v;
    }
    atomicAdd(&stats[t], s);
    atomicAdd(&stats[NF + t], s2);
}

// ---------------- kernel 7: GEMM2 MFMA + inline BN1+relu + node-att -------
__global__ __launch_bounds__(256) void k_gemm2_bn_att(const float* __restrict__ A,
        const float* __restrict__ stats, const float* __restrict__ g,
        const float* __restrict__ bb, const ushort* __restrict__ BT,
        const float* __restrict__ atts, const float* __restrict__ attd,
        ushort* __restrict__ Cb, float* __restrict__ as_, float* __restrict__ ad_) {
    __shared__ ushort As[128][40];   // [m][k], +8 pad
    __shared__ ushort Bs[128][40];   // [n][k], +8 pad
    __shared__ float s_scale[512], s_shift[512];
    __shared__ float s_ps[2][128], s_pd[2][128];
    int t = threadIdx.x;
    const float invn = 1.0f / (float)NN;
    {
        int j = t;
#pragma unroll
        for (int rep = 0; rep < 2; rep++, j += 256) {
            float mu = stats[j] * invn;
            float var = stats[NF + j] * invn - mu * mu;
            float sc = rsqrtf(var + 1e-5f) * g[j];
            s_scale[j] = sc;
            s_shift[j] = bb[j] - mu * sc;
        }
    }
    int head = blockIdx.x;
    int rowBase = blockIdx.y * 128, colBase = head * 128;
    int w = t >> 6, lane = t & 63;
    int wm = (w >> 1) * 64, wn = (w & 1) * 64;
    int lm = lane & 15, q = lane >> 4;
    f32x4 acc[4][4] = {};
    int sr = t >> 2, sk = (t & 3) * 8;
    for (int k0 = 0; k0 < 512; k0 += 32) {
        __syncthreads();
        int jb = k0 + sk;
        float sc[8], sh[8];
#pragma unroll
        for (int c = 0; c < 8; c++) { sc[c] = s_scale[jb + c]; sh[c] = s_shift[jb + c]; }
        const float* Ap0 = &A[(rowBase + sr) * 512 + jb];
        const float* Ap1 = Ap0 + 64 * 512;
        float4 a00 = *(const float4*)Ap0, a01 = *(const float4*)(Ap0 + 4);
        float4 a10 = *(const float4*)Ap1, a11 = *(const float4*)(Ap1 + 4);
        uint4 b0 = *(const uint4*)&BT[(colBase + sr) * 512 + jb];
        uint4 b1 = *(const uint4*)&BT[(colBase + 64 + sr) * 512 + jb];
        ushort pa0[8], pa1[8];
        const float* f0 = &a00.x; const float* f1 = &a10.x;
#pragma unroll
        for (int c = 0; c < 4; c++) {
            pa0[c] = f2bf(fmaxf(f0[c] * sc[c] + sh[c], 0.f));
            pa1[c] = f2bf(fmaxf(f1[c] * sc[c] + sh[c], 0.f));
        }
        const float* f2 = &a01.x; const float* f3 = &a11.x;
#pragma unroll
        for (int c = 0; c < 4; c++) {
            pa0[4 + c] = f2bf(fmaxf(f2[c] * sc[4 + c] + sh[4 + c], 0.f));
            pa1[4 + c] = f2bf(fmaxf(f3[c] * sc[4 + c] + sh[4 + c], 0.f));
        }
        *(uint4*)&As[sr][sk]      = *(uint4*)pa0;
        *(uint4*)&As[64 + sr][sk] = *(uint4*)pa1;
        *(uint4*)&Bs[sr][sk]      = b0;
        *(uint4*)&Bs[64 + sr][sk] = b1;
        __syncthreads();
        bf16x8 af[4], bf[4];
#pragma unroll
        for (int i = 0; i < 4; i++) af[i] = *(const bf16x8*)&As[wm + i * 16 + lm][q * 8];
#pragma unroll
        for (int j = 0; j < 4; j++) bf[j] = *(const bf16x8*)&Bs[wn + j * 16 + lm][q * 8];
#pragma unroll
        for (int i = 0; i < 4; i++)
#pragma unroll
            for (int j = 0; j < 4; j++)
                acc[i][j] = __builtin_amdgcn_mfma_f32_16x16x32_bf16(af[i], bf[j], acc[i][j], 0, 0, 0);
    }
    // C store (bf16)
#pragma unroll
    for (int i = 0; i < 4; i++) {
        int row = rowBase + wm + i * 16 + q * 4;
#pragma unroll
        for (int j = 0; j < 4; j++) {
            int col = colBase + wn + j * 16 + lm;
#pragma unroll
            for (int r = 0; r < 4; r++)
                Cb[(row + r) * 512 + col] = f2bf(acc[i][j][r]);
        }
    }
    // node-att epilogue: complete head dot for this block's 128 rows
    float sa[4], da[4];
#pragma unroll
    for (int j = 0; j < 4; j++) {
        int col = colBase + wn + j * 16 + lm;
        sa[j] = atts[col]; da[j] = attd[col];
    }
#pragma unroll
    for (int i = 0; i < 4; i++) {
#pragma unroll
        for (int r = 0; r < 4; r++) {
            float ps = 0.f, pd = 0.f;
#pragma unroll
            for (int j = 0; j < 4; j++) {
                float c = acc[i][j][r];
                ps += c * sa[j]; pd += c * da[j];
            }
#pragma unroll
            for (int o = 1; o < 16; o <<= 1) { ps += __shfl_xor(ps, o); pd += __shfl_xor(pd, o); }
            if (lm == 0) {
                int row = wm + i * 16 + q * 4 + r;
                s_ps[w & 1][row] = ps; s_pd[w & 1][row] = pd;
            }
        }
    }
    __syncthreads();
    if (t < 128) {
        as_[(rowBase + t) * 4 + head] = s_ps[0][t] + s_ps[1][t];
    } else {
        int row = t - 128;
        ad_[(rowBase + row) * 4 + head] = s_pd[0][row] + s_pd[1][row];
    }
}

// ---------------- kernel 8: FC MFMA with inline BN2+relu + mask + adj -----
__global__ __launch_bounds__(64) void k_fc_bn(const float* __restrict__ e2,
        const float* __restrict__ stats, const float* __restrict__ g,
        const float* __restrict__ bb, const ushort* __restrict__ WfcT,
        const float* __restrict__ bfc, const int* __restrict__ mask,
        const float* __restrict__ adj, float* __restrict__ out) {
    __shared__ float s_scale[512], s_shift[512];
    int lane = threadIdx.x;
    const float invn = 1.0f / (float)NN;
    for (int j = lane; j < 512; j += 64) {
        float mu = stats[j] * invn;
        float var = stats[NF + j] * invn - mu * mu;
        float sc = rsqrtf(var + 1e-5f) * g[j];
        s_scale[j] = sc;
        s_shift[j] = bb[j] - mu * sc;
    }
    __syncthreads();
    int r0 = blockIdx.x * 16;
    int lm = lane & 15, q = lane >> 4;
    f32x4 acc[3] = {};
#pragma unroll
    for (int k0 = 0; k0 < 512; k0 += 32) {
        int jb = k0 + q * 8;
        const float* p = &e2[(r0 + lm) * 512 + jb];
        float4 v0 = *(const float4*)p, v1 = *(const float4*)(p + 4);
        ushort pa[8];
        const float* f0 = &v0.x; const float* f1 = &v1.x;
#pragma unroll
        for (int c = 0; c < 4; c++) {
            pa[c]     = f2bf(fmaxf(f0[c] * s_scale[jb + c] + s_shift[jb + c], 0.f));
            pa[4 + c] = f2bf(fmaxf(f1[c] * s_scale[jb + 4 + c] + s_shift[jb + 4 + c], 0.f));
        }
        bf16x8 af = *(const bf16x8*)pa;
#pragma unroll
        for (int jt = 0; jt < 3; jt++) {
            bf16x8 bf = *(const bf16x8*)&WfcT[(jt * 16 + lm) * 512 + k0 + q * 8];
            acc[jt] = __builtin_amdgcn_mfma_f32_16x16x32_bf16(af, bf, acc[jt], 0, 0, 0);
        }
    }
#pragma unroll
    for (int jt = 0; jt < 3; jt++) {
        int col = jt * 16 + lm;
        if (col < OUTE) {
#pragma unroll
            for (int r = 0; r < 4; r++) {
                int n = r0 + q * 4 + r;
                float v = acc[jt][r] + bfc[col];
                v = mask[n] ? v : 0.f;
                out[n * OUTE + col] = v + adj[n * OUTE + col];
            }
        }
    }
}

// ---------------- host side ----------------------------------------------
extern "C" void kernel_launch(void* const* d_in, const int* in_sizes, int n_in,
                              void* d_out, int out_size, void* d_ws, size_t ws_size,
                              hipStream_t stream) {
    const float* x       = (const float*)d_in[0];
    const int*   ei      = (const int*)d_in[1];
    const float* pos     = (const float*)d_in[2];
    const int*   mask    = (const int*)d_in[3];
    const float* adj     = (const float*)d_in[4];
    const float* W1      = (const float*)d_in[5];
    const float* atts1   = (const float*)d_in[6];
    const float* attd1   = (const float*)d_in[7];
    const float* We1     = (const float*)d_in[8];
    const float* atte1   = (const float*)d_in[9];
    const float* bias1   = (const float*)d_in[10];
    const float* g1      = (const float*)d_in[11];
    const float* be1     = (const float*)d_in[12];
    const float* W2      = (const float*)d_in[13];
    const float* atts2   = (const float*)d_in[14];
    const float* attd2   = (const float*)d_in[15];
    const float* We2     = (const float*)d_in[16];
    const float* atte2   = (const float*)d_in[17];
    const float* bias2   = (const float*)d_in[18];
    const float* g2      = (const float*)d_in[19];
    const float* be2     = (const float*)d_in[20];
    const float* Wfc     = (const float*)d_in[21];
    const float* bfc     = (const float*)d_in[22];
    float* out = (float*)d_out;

    // workspace layout (float-element offsets; 16B-aligned blocks)
    char* ws = (char*)d_ws;
    int*    deg     = (int*)(ws);                       // 2560
    int*    cursor  = (int*)(ws + 2560 * 4);            // 2560
    float*  stats   = (float*)(ws + 5120 * 4);          // 2048 (L1:1024, L2:1024)
    // ---- zero region = first 7168 elements ----
    int*    offs    = (int*)(ws + 7168 * 4);            // 2561 (pad to 2576)
    float*  dote    = (float*)(ws + 9744 * 4);          // 8 (pad 16)
    int2*   csrp    = (int2*)(ws + 9760 * 4);           // 163840 int2 = 327680 ints
    float*  as_     = (float*)(ws + 337440 * 4);        // 10240
    float*  ad_     = (float*)(ws + 347680 * 4);        // 10240
    float*  t1      = (float*)(ws + 357920 * 4);        // 1310720 (agg out, BN input)
    ushort* hb      = (ushort*)(ws + 1668640 * 4);      // 1310720 bf16 (h for agg/att)
    ushort* W2T     = (ushort*)(ws + 2324000 * 4);      // 262144 bf16
    ushort* WfcT    = (ushort*)(ws + 2455072 * 4);      // 24576 bf16 [48][512]
    // total ~2.47M floats = ~9.9 MB

    hipMemsetAsync(d_ws, 0, 7168 * 4, stream);

    // graph structure + weight prep (separate launches — see R7 note)
    k_prep<<<802, 256, 0, stream>>>(ei, deg, We1, atte1, We2, atte2, dote, Wfc, WfcT, W2, W2T);
    k_scan<<<1, 256, 0, stream>>>(deg, offs);
    k_csr_fill<<<NE / 256, 256, 0, stream>>>(ei, pos, offs, cursor, csrp);

    // ---- layer 1 ----
    k_gemm1_att<<<NN / 4, 256, 0, stream>>>(x, W1, atts1, attd1, hb, as_, ad_);
    k_edge_agg<<<NN, 256, 0, stream>>>(offs, csrp, (const float4*)as_,
                                       (const float4*)ad_, dote, hb, bias1, t1);
    k_bnstats<<<NN / 64, 512, 0, stream>>>(t1, stats);

    // ---- layer 2 (BN1 inline in GEMM2 A-staging; node-att in epilogue) ----
    k_gemm2_bn_att<<<dim3(4, NN / 128), 256, 0, stream>>>(t1, stats, g1, be1, W2T,
                                                          atts2, attd2, hb, as_, ad_);
    k_edge_agg<<<NN, 256, 0, stream>>>(offs, csrp, (const float4*)as_,
                                       (const float4*)ad_, dote + 4, hb, bias2, t1);
    k_bnstats<<<NN / 64, 512, 0, stream>>>(t1, stats + 1024);

    // ---- head (BN2 inline in FC A-fragment load) ----
    k_fc_bn<<<NN / 16, 64, 0, stream>>>(t1, stats + 1024, g2, be2, WfcT, bfc, mask, adj, out);
}